// Round 15
// baseline (64.752 us; speedup 1.0000x reference)
//
#include <hip/hip_runtime.h>
#include <math.h>

#define TT 16
#define CC 2048
#define NEGV -1.0e30f
#define CW 256              // GEMM chunk width (floats)
#define NCK (CC / CW)       // 8 chunks
#define ASTR 260            // A/B LDS row stride (floats)
#define BUFE (TT * ASTR)    // one staging buffer (floats)
#define SSTR 17             // softmax / cumsum scratch stride
#define PSTR 48             // Pm row stride: 4-row strided reads -> 2-way (free)
#define DSTR 48             // Dm row stride: same

#define KEEP(x) asm volatile("" : "+v"(x))

// DPP rotate within each 16-lane row: dst lane j <- src lane (j-n)&15 (HW dir
// doesn't matter for correctness: masks are derived by rotating the lane id).
#define RORF(dst, src, n)                                                      \
    dst = __int_as_float(__builtin_amdgcn_update_dpp(                          \
        0, __float_as_int(src), 0x120 + (n), 0xF, 0xF, false))

__global__ __launch_bounds__(1024, 1) void cpa_kernel(
    const float* __restrict__ f1, const float* __restrict__ f2,
    float* __restrict__ out, int B)
{
    __shared__ float  As[2 * BUFE];   // double-buffered A staging
    __shared__ float  Bs[2 * BUFE];   // double-buffered B staging
    __shared__ float4 part4[256];
    __shared__ float  Ps[TT * SSTR];  // softmax output (pre-cumsum)
    __shared__ float  Pq[TT * SSTR];  // after pass-1 (column prefix)
    __shared__ float  Pm[TT * PSTR];  // final 2D cumsum
    __shared__ float  Dm[2 * TT * DSTR];
    __shared__ float  fin[TT];

    const int b    = blockIdx.x;
    const int tid  = threadIdx.x;
    const int wv   = tid >> 6;
    const int lane = tid & 63;

    // ===== GEMM: wave (ti,tj) owns a 4x4 tile. r10's register shape (one  =====
    // ===== named av/bv pair, NON-unrolled loop) + dbuf LDS -> ONE barrier =====
    // ===== per chunk (8 vs 16). Race-free: iter ck+1 writes the OTHER     =====
    // ===== buffer than iter ck's readers; the barrier orders write->read. =====
    const int ti = wv >> 2, tj = wv & 3;
    const float* baseA = f1 + (size_t)b * TT * CC;
    const float* baseB = f2 + (size_t)b * TT * CC;

    float4 av = *(const float4*)(baseA + wv * CC + lane * 4);
    float4 bv = *(const float4*)(baseB + wv * CC + lane * 4);

    float acc[4][4] = {};
    for (int ck = 0; ck < NCK; ++ck) {
        float* Ab = As + (ck & 1) * BUFE;
        float* Bb = Bs + (ck & 1) * BUFE;
        *(float4*)&Ab[wv * ASTR + lane * 4] = av;
        *(float4*)&Bb[wv * ASTR + lane * 4] = bv;
        __syncthreads();   // writes(ck) visible; implies compute(ck-1) done
        if (ck + 1 < NCK) {   // prefetch next chunk; used at next iter's write
            av = *(const float4*)(baseA + wv * CC + (ck + 1) * CW + lane * 4);
            bv = *(const float4*)(baseB + wv * CC + (ck + 1) * CW + lane * 4);
        }
        float4 bn[4];
        #pragma unroll
        for (int n = 0; n < 4; ++n)
            bn[n] = *(const float4*)&Bb[(tj * 4 + n) * ASTR + lane * 4];
        #pragma unroll
        for (int m = 0; m < 4; ++m) {
            float4 am = *(const float4*)&Ab[(ti * 4 + m) * ASTR + lane * 4];
            #pragma unroll
            for (int n = 0; n < 4; ++n) {
                acc[m][n] = fmaf(am.x, bn[n].x, acc[m][n]);
                acc[m][n] = fmaf(am.y, bn[n].y, acc[m][n]);
                acc[m][n] = fmaf(am.z, bn[n].z, acc[m][n]);
                acc[m][n] = fmaf(am.w, bn[n].w, acc[m][n]);
            }
        }
    }
    // in-wave K-reduce over each 16-lane group via DPP rotations (VALU pipe)
    #pragma unroll
    for (int m = 0; m < 4; ++m) {
        #pragma unroll
        for (int n = 0; n < 4; ++n) {
            float v = acc[m][n], t;
            RORF(t, v, 1); v += t;
            RORF(t, v, 2); v += t;
            RORF(t, v, 4); v += t;
            RORF(t, v, 8); v += t;
            if ((lane & 15) == 0)   // one writer per 16-lane group
                ((float*)&part4[(ti * 4 + m) * 16 + (tj * 4 + n)])[lane >> 4] = v;
        }
    }
    __syncthreads();

    // ================= softmax (rows) =================
    if (tid < 256) {
        const int si = tid >> 4, sj = tid & 15;
        float4 p = part4[tid];
        float s = (p.x + p.y + p.z + p.w) * (1.0f / sqrtf((float)CC));
        float mx = s;
        #pragma unroll
        for (int d = 1; d < 16; d <<= 1) mx = fmaxf(mx, __shfl_xor(mx, d));
        const float e = expf(s - mx);
        float sm = e;
        #pragma unroll
        for (int d = 1; d < 16; d <<= 1) sm += __shfl_xor(sm, d);
        Ps[si * SSTR + sj] = e / sm;
    }
    __syncthreads();

    // ======= 2D cumsum: per-thread register folds in EXACT numpy order =======
    // (association is load-bearing: DP increments tie at exactly 0.0 and the
    //  argmax is first-occurrence, so each element must be ((v0+v1)+...)+vr)
    if (tid < 256) {   // pass 1: prefix over rows (axis -2), column c
        const int r = tid >> 4, c = tid & 15;
        float run = Ps[c];
        #pragma unroll
        for (int rr = 1; rr < TT; ++rr)
            if (rr <= r) run += Ps[rr * SSTR + c];
        Pq[r * SSTR + c] = run;
    }
    __syncthreads();
    if (tid < 256) {   // pass 2: prefix over cols (axis -1), row r
        const int r = tid >> 4, c = tid & 15;
        float run = Pq[r * SSTR];
        #pragma unroll
        for (int cc = 1; cc < TT; ++cc)
            if (cc <= c) run += Pq[r * SSTR + cc];
        Pm[r * PSTR + c] = run;
    }
    __syncthreads();

    // ================= DP precompute (DPP-rotation based) =================
    // wave -> output row i (balanced so each SIMD gets equal masked work)
    const int i_dp = (int)((0x612073458ABC9DEFull >> (4 * wv)) & 15);
    const int ksD  = lane >> 4;
    const int j    = lane & 15;
    const float jf = (float)j;

    const float pij = Pm[i_dp * PSTR + j];
    float vA0 = Pm[(ksD +  0) * PSTR + j];
    float vA1 = Pm[(ksD +  4) * PSTR + j];
    float vA2 = Pm[(ksD +  8) * PSTR + j];
    float vA3 = Pm[(ksD + 12) * PSTR + j];
    float ca0, ca1, ca2, ca3, ra0, ra1, ra2, ra3;
    {
        int a, d1;
        a = ksD;      ca0 = -vA0 + (a < i_dp ? 0.f : NEGV); d1 = i_dp - a; if (d1 < 1) d1 = 1; ra0 = rsqrtf((float)d1);
        a = ksD + 4;  ca1 = -vA1 + (a < i_dp ? 0.f : NEGV); d1 = i_dp - a; if (d1 < 1) d1 = 1; ra1 = rsqrtf((float)d1);
        a = ksD + 8;  ca2 = -vA2 + (a < i_dp ? 0.f : NEGV); d1 = i_dp - a; if (d1 < 1) d1 = 1; ra2 = rsqrtf((float)d1);
        a = ksD + 12; ca3 = -vA3 + (a < i_dp ? 0.f : NEGV); d1 = i_dp - a; if (d1 < 1) d1 = 1; ra3 = rsqrtf((float)d1);
    }

    float qr[4][16];
    // t = 0: bb == j -> masked; area clamp -> rjt = 1
    qr[0][0] = (ca0 + NEGV + vA0) * ra0; KEEP(qr[0][0]);
    qr[1][0] = (ca1 + NEGV + vA1) * ra1; KEEP(qr[1][0]);
    qr[2][0] = (ca2 + NEGV + vA2) * ra2; KEEP(qr[2][0]);
    qr[3][0] = (ca3 + NEGV + vA3) * ra3; KEEP(qr[3][0]);

#define QSTEP(n)                                                               \
    {                                                                          \
        float bbf, rIt, rAt;                                                   \
        RORF(bbf, jf, n);                                                      \
        RORF(rIt, pij, n);                                                     \
        const int bbi = (int)bbf;                                              \
        int d2 = j - bbi; if (d2 < 1) d2 = 1;                                  \
        const float rjt = rsqrtf((float)d2);                                   \
        const float cbm = pij - rIt + ((bbi < j) ? 0.0f : NEGV);               \
        RORF(rAt, vA0, n); qr[0][n] = (ca0 + cbm + rAt) * (ra0 * rjt); KEEP(qr[0][n]); \
        RORF(rAt, vA1, n); qr[1][n] = (ca1 + cbm + rAt) * (ra1 * rjt); KEEP(qr[1][n]); \
        RORF(rAt, vA2, n); qr[2][n] = (ca2 + cbm + rAt) * (ra2 * rjt); KEEP(qr[2][n]); \
        RORF(rAt, vA3, n); qr[3][n] = (ca3 + cbm + rAt) * (ra3 * rjt); KEEP(qr[3][n]); \
    }
    QSTEP(1)  QSTEP(2)  QSTEP(3)  QSTEP(4)  QSTEP(5)  QSTEP(6)  QSTEP(7)
    QSTEP(8)  QSTEP(9)  QSTEP(10) QSTEP(11) QSTEP(12) QSTEP(13) QSTEP(14) QSTEP(15)
#undef QSTEP

    const float D0 = pij / (float)((i_dp + 1) * (j + 1));
    if (ksD == 0) Dm[i_dp * DSTR + j] = D0;
    if (wv == 0 && lane == 15) fin[0] = D0;   // imap[0]=15 -> (15,15)
    __syncthreads();

    // ================= DP: 15 steps, DPP-systolic, k-windowed =================
    // Row window: D_k rows i < k retired (garbage never wins). Candidate
    // window: a in [k-1, i) -> blocks [tlo, nA). Rotation window: at step k,
    // rotation n > 16-k is dead for EVERY lane. All three windows drop only
    // always-losing candidates; fmaxf reorder is exact -> fin[] bit-identical
    // to the full 256-candidate version. (r9/r10-verified.)
    const int nA = (i_dp + 3) >> 2;   // wave-uniform masked trip count

#define DSTEP(A_, n, MACC)                                                     \
    { float dt_; RORF(dt_, dbase, n); MACC = fmaxf(MACC, dt_ + qr[A_][n]); }
#define AABLOCK(A_, TLO_, NM_)                                                 \
    if (A_ >= (TLO_) && A_ < nA) {                                             \
        const float dbase = Dold[(ksD + A_ * 4) * DSTR + j];                   \
        m0 = fmaxf(m0, dbase + qr[A_][0]);                                     \
        if (1  <= (NM_)) DSTEP(A_, 1, m1)                                      \
        if (2  <= (NM_)) DSTEP(A_, 2, m2)                                      \
        if (3  <= (NM_)) DSTEP(A_, 3, m3)                                      \
        if (4  <= (NM_)) DSTEP(A_, 4, m0)                                      \
        if (5  <= (NM_)) DSTEP(A_, 5, m1)                                      \
        if (6  <= (NM_)) DSTEP(A_, 6, m2)                                      \
        if (7  <= (NM_)) DSTEP(A_, 7, m3)                                      \
        if (8  <= (NM_)) DSTEP(A_, 8, m0)                                      \
        if (9  <= (NM_)) DSTEP(A_, 9, m1)                                      \
        if (10 <= (NM_)) DSTEP(A_, 10, m2)                                     \
        if (11 <= (NM_)) DSTEP(A_, 11, m3)                                     \
        if (12 <= (NM_)) DSTEP(A_, 12, m0)                                     \
        if (13 <= (NM_)) DSTEP(A_, 13, m1)                                     \
        if (14 <= (NM_)) DSTEP(A_, 14, m2)                                     \
        if (15 <= (NM_)) DSTEP(A_, 15, m3)                                     \
    }

    #pragma unroll
    for (int k = 1; k < TT; ++k) {
        const float* Dold = Dm + ((k - 1) & 1) * (TT * DSTR);
        float*       Dnew = Dm + (k & 1)       * (TT * DSTR);
        if (i_dp >= k) {
            const int tlo  = (k - 1) >> 2;    // compile-time after unroll
            const int nmax = 16 - k;          // rotation window, compile-time
            float m0 = -3.0e38f, m1 = -3.0e38f, m2 = -3.0e38f, m3 = -3.0e38f;
            AABLOCK(0, tlo, nmax)
            AABLOCK(1, tlo, nmax)
            AABLOCK(2, tlo, nmax)
            AABLOCK(3, tlo, nmax)
            float mm = fmaxf(fmaxf(m0, m1), fmaxf(m2, m3));
            mm = fmaxf(mm, __shfl_xor(mm, 16));
            mm = fmaxf(mm, __shfl_xor(mm, 32));
            if (ksD == 0) Dnew[i_dp * DSTR + j] = mm;
            if (wv == 0 && lane == 15) fin[k] = mm;
        } else if (ksD == 0) {
            Dnew[i_dp * DSTR + j] = -3.0e38f;  // retired row: garbage, never wins
        }
        __syncthreads();
    }
#undef AABLOCK
#undef DSTEP

    // ================= finalize: serial first-occurrence argmax =================
    if (tid == 0) {
        float best = fin[0];
        int   idx  = 0;
        #pragma unroll
        for (int k = 1; k < TT; ++k) {
            if (fin[k] > best) { best = fin[k]; idx = k; }
        }
        out[b]     = -best;
        out[B + b] = (float)idx;
    }
}

extern "C" void kernel_launch(void* const* d_in, const int* in_sizes, int n_in,
                              void* d_out, int out_size, void* d_ws, size_t ws_size,
                              hipStream_t stream)
{
    const float* f1 = (const float*)d_in[0];
    const float* f2 = (const float*)d_in[1];
    float* out = (float*)d_out;
    const int B = in_sizes[0] / (TT * CC);   // 256
    hipLaunchKernelGGL(cpa_kernel, dim3(B), dim3(1024), 0, stream, f1, f2, out, B);
}

// Round 16
// 30.967 us; speedup vs baseline: 2.0910x; 2.0910x over previous
//
#include <hip/hip_runtime.h>
#include <math.h>

#define TT 16
#define CC 2048
#define NEGV -1.0e30f
#define CW 256              // GEMM chunk width (floats)
#define NCK (CC / CW)       // 8 chunks
#define ASTR 260            // A/B LDS row stride (floats)
#define BUFE (TT * ASTR)    // one staging buffer (floats)
#define SSTR 17             // softmax / cumsum scratch stride
#define PSTR 48             // Pm row stride: 4-row strided reads -> 2-way (free)
#define DSTR 48             // Dm row stride: same

#define KEEP(x) asm volatile("" : "+v"(x))

// DPP rotate within each 16-lane row: dst lane j <- src lane (j-n)&15 (HW dir
// doesn't matter for correctness: masks are derived by rotating the lane id).
#define RORF(dst, src, n)                                                      \
    dst = __int_as_float(__builtin_amdgcn_update_dpp(                          \
        0, __float_as_int(src), 0x120 + (n), 0xF, 0xF, false))

__global__ __launch_bounds__(1024, 1) void cpa_kernel(
    const float* __restrict__ f1, const float* __restrict__ f2,
    float* __restrict__ out, int B)
{
    __shared__ float  As[2 * BUFE];   // double-buffered A staging
    __shared__ float  Bs[2 * BUFE];   // double-buffered B staging
    __shared__ float4 part4[256];
    __shared__ float  Ps[TT * SSTR];  // softmax output (pre-cumsum)
    __shared__ float  Pq[TT * SSTR];  // after pass-1 (column prefix)
    __shared__ float  Pm[TT * PSTR];  // final 2D cumsum
    __shared__ float  Dm[2 * TT * DSTR];
    __shared__ float  fin[TT];

    const int b    = blockIdx.x;
    const int tid  = threadIdx.x;
    const int wv   = tid >> 6;
    const int lane = tid & 63;

    // ===== GEMM: wave (ti,tj) owns a 4x4 tile. Single-barrier dbuf:        =====
    // ===== unroll(disable) prevents the x2 unroll that spilled r15 (parity =====
    // ===== made static doubled av/bv live ranges); parity is one XOR/iter. =====
    // ===== Race-proof: iter ck+1 writes the buffer iter-ck readers do NOT  =====
    // ===== read; the barrier orders same-parity write->read; a buffer is   =====
    // ===== overwritten only after a barrier all its readers passed.        =====
    const int ti = wv >> 2, tj = wv & 3;
    const float* baseA = f1 + (size_t)b * TT * CC;
    const float* baseB = f2 + (size_t)b * TT * CC;
    const int wvo = wv * ASTR + lane * 4;   // staging write offset (floats)

    float4 av = *(const float4*)(baseA + wv * CC + lane * 4);
    float4 bv = *(const float4*)(baseB + wv * CC + lane * 4);

    float acc[4][4] = {};
    int off = 0;
    #pragma clang loop unroll(disable)
    for (int ck = 0; ck < NCK; ++ck) {
        float* Ab = As + off;
        float* Bb = Bs + off;
        *(float4*)&Ab[wvo] = av;
        *(float4*)&Bb[wvo] = bv;
        __syncthreads();   // writes(ck) visible; prior-parity readers done
        if (ck + 1 < NCK) {   // prefetch next chunk; used at next iter's write
            av = *(const float4*)(baseA + wv * CC + (ck + 1) * CW + lane * 4);
            bv = *(const float4*)(baseB + wv * CC + (ck + 1) * CW + lane * 4);
        }
        float4 bn[4];
        #pragma unroll
        for (int n = 0; n < 4; ++n)
            bn[n] = *(const float4*)&Bb[(tj * 4 + n) * ASTR + lane * 4];
        #pragma unroll
        for (int m = 0; m < 4; ++m) {
            float4 am = *(const float4*)&Ab[(ti * 4 + m) * ASTR + lane * 4];
            #pragma unroll
            for (int n = 0; n < 4; ++n) {
                acc[m][n] = fmaf(am.x, bn[n].x, acc[m][n]);
                acc[m][n] = fmaf(am.y, bn[n].y, acc[m][n]);
                acc[m][n] = fmaf(am.z, bn[n].z, acc[m][n]);
                acc[m][n] = fmaf(am.w, bn[n].w, acc[m][n]);
            }
        }
        off ^= BUFE;
    }
    // in-wave K-reduce over each 16-lane group via DPP rotations (VALU pipe)
    #pragma unroll
    for (int m = 0; m < 4; ++m) {
        #pragma unroll
        for (int n = 0; n < 4; ++n) {
            float v = acc[m][n], t;
            RORF(t, v, 1); v += t;
            RORF(t, v, 2); v += t;
            RORF(t, v, 4); v += t;
            RORF(t, v, 8); v += t;
            if ((lane & 15) == 0)   // one writer per 16-lane group
                ((float*)&part4[(ti * 4 + m) * 16 + (tj * 4 + n)])[lane >> 4] = v;
        }
    }
    __syncthreads();

    // ================= softmax (rows) =================
    if (tid < 256) {
        const int si = tid >> 4, sj = tid & 15;
        float4 p = part4[tid];
        float s = (p.x + p.y + p.z + p.w) * (1.0f / sqrtf((float)CC));
        float mx = s;
        #pragma unroll
        for (int d = 1; d < 16; d <<= 1) mx = fmaxf(mx, __shfl_xor(mx, d));
        const float e = expf(s - mx);
        float sm = e;
        #pragma unroll
        for (int d = 1; d < 16; d <<= 1) sm += __shfl_xor(sm, d);
        Ps[si * SSTR + sj] = e / sm;
    }
    __syncthreads();

    // ======= 2D cumsum: per-thread register folds in EXACT numpy order =======
    // (association is load-bearing: DP increments tie at exactly 0.0 and the
    //  argmax is first-occurrence, so each element must be ((v0+v1)+...)+vr)
    if (tid < 256) {   // pass 1: prefix over rows (axis -2), column c
        const int r = tid >> 4, c = tid & 15;
        float run = Ps[c];
        #pragma unroll
        for (int rr = 1; rr < TT; ++rr)
            if (rr <= r) run += Ps[rr * SSTR + c];
        Pq[r * SSTR + c] = run;
    }
    __syncthreads();
    if (tid < 256) {   // pass 2: prefix over cols (axis -1), row r
        const int r = tid >> 4, c = tid & 15;
        float run = Pq[r * SSTR];
        #pragma unroll
        for (int cc = 1; cc < TT; ++cc)
            if (cc <= c) run += Pq[r * SSTR + cc];
        Pm[r * PSTR + c] = run;
    }
    __syncthreads();

    // ================= DP precompute (DPP-rotation based) =================
    // wave -> output row i (balanced so each SIMD gets equal masked work)
    const int i_dp = (int)((0x612073458ABC9DEFull >> (4 * wv)) & 15);
    const int ksD  = lane >> 4;
    const int j    = lane & 15;
    const float jf = (float)j;

    const float pij = Pm[i_dp * PSTR + j];
    float vA0 = Pm[(ksD +  0) * PSTR + j];
    float vA1 = Pm[(ksD +  4) * PSTR + j];
    float vA2 = Pm[(ksD +  8) * PSTR + j];
    float vA3 = Pm[(ksD + 12) * PSTR + j];
    float ca0, ca1, ca2, ca3, ra0, ra1, ra2, ra3;
    {
        int a, d1;
        a = ksD;      ca0 = -vA0 + (a < i_dp ? 0.f : NEGV); d1 = i_dp - a; if (d1 < 1) d1 = 1; ra0 = rsqrtf((float)d1);
        a = ksD + 4;  ca1 = -vA1 + (a < i_dp ? 0.f : NEGV); d1 = i_dp - a; if (d1 < 1) d1 = 1; ra1 = rsqrtf((float)d1);
        a = ksD + 8;  ca2 = -vA2 + (a < i_dp ? 0.f : NEGV); d1 = i_dp - a; if (d1 < 1) d1 = 1; ra2 = rsqrtf((float)d1);
        a = ksD + 12; ca3 = -vA3 + (a < i_dp ? 0.f : NEGV); d1 = i_dp - a; if (d1 < 1) d1 = 1; ra3 = rsqrtf((float)d1);
    }

    float qr[4][16];
    // t = 0: bb == j -> masked; area clamp -> rjt = 1
    qr[0][0] = (ca0 + NEGV + vA0) * ra0; KEEP(qr[0][0]);
    qr[1][0] = (ca1 + NEGV + vA1) * ra1; KEEP(qr[1][0]);
    qr[2][0] = (ca2 + NEGV + vA2) * ra2; KEEP(qr[2][0]);
    qr[3][0] = (ca3 + NEGV + vA3) * ra3; KEEP(qr[3][0]);

#define QSTEP(n)                                                               \
    {                                                                          \
        float bbf, rIt, rAt;                                                   \
        RORF(bbf, jf, n);                                                      \
        RORF(rIt, pij, n);                                                     \
        const int bbi = (int)bbf;                                              \
        int d2 = j - bbi; if (d2 < 1) d2 = 1;                                  \
        const float rjt = rsqrtf((float)d2);                                   \
        const float cbm = pij - rIt + ((bbi < j) ? 0.0f : NEGV);               \
        RORF(rAt, vA0, n); qr[0][n] = (ca0 + cbm + rAt) * (ra0 * rjt); KEEP(qr[0][n]); \
        RORF(rAt, vA1, n); qr[1][n] = (ca1 + cbm + rAt) * (ra1 * rjt); KEEP(qr[1][n]); \
        RORF(rAt, vA2, n); qr[2][n] = (ca2 + cbm + rAt) * (ra2 * rjt); KEEP(qr[2][n]); \
        RORF(rAt, vA3, n); qr[3][n] = (ca3 + cbm + rAt) * (ra3 * rjt); KEEP(qr[3][n]); \
    }
    QSTEP(1)  QSTEP(2)  QSTEP(3)  QSTEP(4)  QSTEP(5)  QSTEP(6)  QSTEP(7)
    QSTEP(8)  QSTEP(9)  QSTEP(10) QSTEP(11) QSTEP(12) QSTEP(13) QSTEP(14) QSTEP(15)
#undef QSTEP

    const float D0 = pij / (float)((i_dp + 1) * (j + 1));
    if (ksD == 0) Dm[i_dp * DSTR + j] = D0;
    if (wv == 0 && lane == 15) fin[0] = D0;   // imap[0]=15 -> (15,15)
    __syncthreads();

    // ================= DP: 15 steps, DPP-systolic, k-windowed =================
    // Row window: D_k rows i < k retired (garbage never wins). Candidate
    // window: a in [k-1, i) -> blocks [tlo, nA). Rotation window: at step k,
    // rotation n > 16-k is dead for EVERY lane. All three windows drop only
    // always-losing candidates; fmaxf reorder is exact -> fin[] bit-identical
    // to the full 256-candidate version. (r9/r10-verified.)
    const int nA = (i_dp + 3) >> 2;   // wave-uniform masked trip count

#define DSTEP(A_, n, MACC)                                                     \
    { float dt_; RORF(dt_, dbase, n); MACC = fmaxf(MACC, dt_ + qr[A_][n]); }
#define AABLOCK(A_, TLO_, NM_)                                                 \
    if (A_ >= (TLO_) && A_ < nA) {                                             \
        const float dbase = Dold[(ksD + A_ * 4) * DSTR + j];                   \
        m0 = fmaxf(m0, dbase + qr[A_][0]);                                     \
        if (1  <= (NM_)) DSTEP(A_, 1, m1)                                      \
        if (2  <= (NM_)) DSTEP(A_, 2, m2)                                      \
        if (3  <= (NM_)) DSTEP(A_, 3, m3)                                      \
        if (4  <= (NM_)) DSTEP(A_, 4, m0)                                      \
        if (5  <= (NM_)) DSTEP(A_, 5, m1)                                      \
        if (6  <= (NM_)) DSTEP(A_, 6, m2)                                      \
        if (7  <= (NM_)) DSTEP(A_, 7, m3)                                      \
        if (8  <= (NM_)) DSTEP(A_, 8, m0)                                      \
        if (9  <= (NM_)) DSTEP(A_, 9, m1)                                      \
        if (10 <= (NM_)) DSTEP(A_, 10, m2)                                     \
        if (11 <= (NM_)) DSTEP(A_, 11, m3)                                     \
        if (12 <= (NM_)) DSTEP(A_, 12, m0)                                     \
        if (13 <= (NM_)) DSTEP(A_, 13, m1)                                     \
        if (14 <= (NM_)) DSTEP(A_, 14, m2)                                     \
        if (15 <= (NM_)) DSTEP(A_, 15, m3)                                     \
    }

    #pragma unroll
    for (int k = 1; k < TT; ++k) {
        const float* Dold = Dm + ((k - 1) & 1) * (TT * DSTR);
        float*       Dnew = Dm + (k & 1)       * (TT * DSTR);
        if (i_dp >= k) {
            const int tlo  = (k - 1) >> 2;    // compile-time after unroll
            const int nmax = 16 - k;          // rotation window, compile-time
            float m0 = -3.0e38f, m1 = -3.0e38f, m2 = -3.0e38f, m3 = -3.0e38f;
            AABLOCK(0, tlo, nmax)
            AABLOCK(1, tlo, nmax)
            AABLOCK(2, tlo, nmax)
            AABLOCK(3, tlo, nmax)
            float mm = fmaxf(fmaxf(m0, m1), fmaxf(m2, m3));
            mm = fmaxf(mm, __shfl_xor(mm, 16));
            mm = fmaxf(mm, __shfl_xor(mm, 32));
            if (ksD == 0) Dnew[i_dp * DSTR + j] = mm;
            if (wv == 0 && lane == 15) fin[k] = mm;
        } else if (ksD == 0) {
            Dnew[i_dp * DSTR + j] = -3.0e38f;  // retired row: garbage, never wins
        }
        __syncthreads();
    }
#undef AABLOCK
#undef DSTEP

    // ================= finalize: serial first-occurrence argmax =================
    if (tid == 0) {
        float best = fin[0];
        int   idx  = 0;
        #pragma unroll
        for (int k = 1; k < TT; ++k) {
            if (fin[k] > best) { best = fin[k]; idx = k; }
        }
        out[b]     = -best;
        out[B + b] = (float)idx;
    }
}

extern "C" void kernel_launch(void* const* d_in, const int* in_sizes, int n_in,
                              void* d_out, int out_size, void* d_ws, size_t ws_size,
                              hipStream_t stream)
{
    const float* f1 = (const float*)d_in[0];
    const float* f2 = (const float*)d_in[1];
    float* out = (float*)d_out;
    const int B = in_sizes[0] / (TT * CC);   // 256
    hipLaunchKernelGGL(cpa_kernel, dim3(B), dim3(1024), 0, stream, f1, f2, out, B);
}

// Round 17
// 28.722 us; speedup vs baseline: 2.2545x; 1.0782x over previous
//
#include <hip/hip_runtime.h>
#include <math.h>

#define TT 16
#define CC 2048
#define NEGV -1.0e30f
#define CW 256              // GEMM chunk width (floats)
#define NCK (CC / CW)       // 8 chunks
#define ASTR 260            // A/B LDS row stride (floats)
#define SSTR 17             // softmax / cumsum scratch stride
#define PSTR 48             // Pm row stride: 4-row strided reads -> 2-way (free)
#define DSTR 48             // Dm row stride: same

#define KEEP(x) asm volatile("" : "+v"(x))

// DPP rotate within each 16-lane row: dst lane j <- src lane (j-n)&15 (HW dir
// doesn't matter for correctness: masks are derived by rotating the lane id).
#define RORF(dst, src, n)                                                      \
    dst = __int_as_float(__builtin_amdgcn_update_dpp(                          \
        0, __float_as_int(src), 0x120 + (n), 0xF, 0xF, false))

__global__ __launch_bounds__(1024, 1) void cpa_kernel(
    const float* __restrict__ f1, const float* __restrict__ f2,
    float* __restrict__ out, int B)
{
    __shared__ float  As[TT * ASTR];  // single-buffer staging (r5/r10 proven)
    __shared__ float  Bs[TT * ASTR];
    __shared__ float4 part4[256];
    __shared__ float  Ps[TT * SSTR];  // softmax output (pre-cumsum)
    __shared__ float  Pq[TT * SSTR];  // after pass-1 (column prefix)
    __shared__ float  Pm[TT * PSTR];  // final 2D cumsum
    __shared__ float  Dm[2 * TT * DSTR];
    __shared__ float  fin[TT];

    const int b    = blockIdx.x;
    const int tid  = threadIdx.x;
    const int wv   = tid >> 6;
    const int lane = tid & 63;

    // ===== GEMM: wave (ti,tj) owns a 4x4 tile — r10's exact structure      =====
    // ===== (write; sync; prefetch; compute; sync). Measured optimum: every =====
    // ===== restructure (dbuf r9/r15/r16, gload_lds r11/r12, split-K r14,   =====
    // ===== deep prefetch r6/r7, direct-global r8) was equal or worse.      =====
    const int ti = wv >> 2, tj = wv & 3;
    const float* baseA = f1 + (size_t)b * TT * CC;
    const float* baseB = f2 + (size_t)b * TT * CC;

    float4 av = *(const float4*)(baseA + wv * CC + lane * 4);
    float4 bv = *(const float4*)(baseB + wv * CC + lane * 4);

    float acc[4][4] = {};
    for (int ck = 0; ck < NCK; ++ck) {
        *(float4*)&As[wv * ASTR + lane * 4] = av;
        *(float4*)&Bs[wv * ASTR + lane * 4] = bv;
        __syncthreads();
        if (ck + 1 < NCK) {   // prefetch next chunk; wait lands at next write
            av = *(const float4*)(baseA + wv * CC + (ck + 1) * CW + lane * 4);
            bv = *(const float4*)(baseB + wv * CC + (ck + 1) * CW + lane * 4);
        }
        float4 bn[4];
        #pragma unroll
        for (int n = 0; n < 4; ++n)
            bn[n] = *(const float4*)&Bs[(tj * 4 + n) * ASTR + lane * 4];
        #pragma unroll
        for (int m = 0; m < 4; ++m) {
            float4 am = *(const float4*)&As[(ti * 4 + m) * ASTR + lane * 4];
            #pragma unroll
            for (int n = 0; n < 4; ++n) {
                acc[m][n] = fmaf(am.x, bn[n].x, acc[m][n]);
                acc[m][n] = fmaf(am.y, bn[n].y, acc[m][n]);
                acc[m][n] = fmaf(am.z, bn[n].z, acc[m][n]);
                acc[m][n] = fmaf(am.w, bn[n].w, acc[m][n]);
            }
        }
        __syncthreads();
    }
    // in-wave K-reduce over each 16-lane group via DPP rotations (VALU pipe)
    #pragma unroll
    for (int m = 0; m < 4; ++m) {
        #pragma unroll
        for (int n = 0; n < 4; ++n) {
            float v = acc[m][n], t;
            RORF(t, v, 1); v += t;
            RORF(t, v, 2); v += t;
            RORF(t, v, 4); v += t;
            RORF(t, v, 8); v += t;
            if ((lane & 15) == 0)   // one writer per 16-lane group
                ((float*)&part4[(ti * 4 + m) * 16 + (tj * 4 + n)])[lane >> 4] = v;
        }
    }
    __syncthreads();

    // ================= softmax (rows) =================
    if (tid < 256) {
        const int si = tid >> 4, sj = tid & 15;
        float4 p = part4[tid];
        float s = (p.x + p.y + p.z + p.w) * (1.0f / sqrtf((float)CC));
        float mx = s;
        #pragma unroll
        for (int d = 1; d < 16; d <<= 1) mx = fmaxf(mx, __shfl_xor(mx, d));
        const float e = expf(s - mx);
        float sm = e;
        #pragma unroll
        for (int d = 1; d < 16; d <<= 1) sm += __shfl_xor(sm, d);
        Ps[si * SSTR + sj] = e / sm;
    }
    __syncthreads();

    // ======= 2D cumsum: per-thread register folds in EXACT numpy order =======
    // (association is load-bearing: DP increments tie at exactly 0.0 and the
    //  argmax is first-occurrence, so each element must be ((v0+v1)+...)+vr)
    if (tid < 256) {   // pass 1: prefix over rows (axis -2), column c
        const int r = tid >> 4, c = tid & 15;
        float run = Ps[c];
        #pragma unroll
        for (int rr = 1; rr < TT; ++rr)
            if (rr <= r) run += Ps[rr * SSTR + c];
        Pq[r * SSTR + c] = run;
    }
    __syncthreads();
    if (tid < 256) {   // pass 2: prefix over cols (axis -1), row r
        const int r = tid >> 4, c = tid & 15;
        float run = Pq[r * SSTR];
        #pragma unroll
        for (int cc = 1; cc < TT; ++cc)
            if (cc <= c) run += Pq[r * SSTR + cc];
        Pm[r * PSTR + c] = run;
    }
    __syncthreads();

    // ================= DP precompute (DPP-rotation based) =================
    // wave -> output row i (balanced so each SIMD gets equal masked work)
    const int i_dp = (int)((0x612073458ABC9DEFull >> (4 * wv)) & 15);
    const int ksD  = lane >> 4;
    const int j    = lane & 15;
    const float jf = (float)j;

    const float pij = Pm[i_dp * PSTR + j];
    float vA0 = Pm[(ksD +  0) * PSTR + j];
    float vA1 = Pm[(ksD +  4) * PSTR + j];
    float vA2 = Pm[(ksD +  8) * PSTR + j];
    float vA3 = Pm[(ksD + 12) * PSTR + j];
    float ca0, ca1, ca2, ca3, ra0, ra1, ra2, ra3;
    {
        int a, d1;
        a = ksD;      ca0 = -vA0 + (a < i_dp ? 0.f : NEGV); d1 = i_dp - a; if (d1 < 1) d1 = 1; ra0 = rsqrtf((float)d1);
        a = ksD + 4;  ca1 = -vA1 + (a < i_dp ? 0.f : NEGV); d1 = i_dp - a; if (d1 < 1) d1 = 1; ra1 = rsqrtf((float)d1);
        a = ksD + 8;  ca2 = -vA2 + (a < i_dp ? 0.f : NEGV); d1 = i_dp - a; if (d1 < 1) d1 = 1; ra2 = rsqrtf((float)d1);
        a = ksD + 12; ca3 = -vA3 + (a < i_dp ? 0.f : NEGV); d1 = i_dp - a; if (d1 < 1) d1 = 1; ra3 = rsqrtf((float)d1);
    }

    float qr[4][16];
    // t = 0: bb == j -> masked; area clamp -> rjt = 1
    qr[0][0] = (ca0 + NEGV + vA0) * ra0; KEEP(qr[0][0]);
    qr[1][0] = (ca1 + NEGV + vA1) * ra1; KEEP(qr[1][0]);
    qr[2][0] = (ca2 + NEGV + vA2) * ra2; KEEP(qr[2][0]);
    qr[3][0] = (ca3 + NEGV + vA3) * ra3; KEEP(qr[3][0]);

#define QSTEP(n)                                                               \
    {                                                                          \
        float bbf, rIt, rAt;                                                   \
        RORF(bbf, jf, n);                                                      \
        RORF(rIt, pij, n);                                                     \
        const int bbi = (int)bbf;                                              \
        int d2 = j - bbi; if (d2 < 1) d2 = 1;                                  \
        const float rjt = rsqrtf((float)d2);                                   \
        const float cbm = pij - rIt + ((bbi < j) ? 0.0f : NEGV);               \
        RORF(rAt, vA0, n); qr[0][n] = (ca0 + cbm + rAt) * (ra0 * rjt); KEEP(qr[0][n]); \
        RORF(rAt, vA1, n); qr[1][n] = (ca1 + cbm + rAt) * (ra1 * rjt); KEEP(qr[1][n]); \
        RORF(rAt, vA2, n); qr[2][n] = (ca2 + cbm + rAt) * (ra2 * rjt); KEEP(qr[2][n]); \
        RORF(rAt, vA3, n); qr[3][n] = (ca3 + cbm + rAt) * (ra3 * rjt); KEEP(qr[3][n]); \
    }
    QSTEP(1)  QSTEP(2)  QSTEP(3)  QSTEP(4)  QSTEP(5)  QSTEP(6)  QSTEP(7)
    QSTEP(8)  QSTEP(9)  QSTEP(10) QSTEP(11) QSTEP(12) QSTEP(13) QSTEP(14) QSTEP(15)
#undef QSTEP

    const float D0 = pij / (float)((i_dp + 1) * (j + 1));
    if (ksD == 0) Dm[i_dp * DSTR + j] = D0;
    if (wv == 0 && lane == 15) fin[0] = D0;   // imap[0]=15 -> (15,15)
    __syncthreads();

    // ================= DP: 15 steps, DPP-systolic, k-windowed =================
    // Row window: D_k rows i < k retired (garbage never wins). Candidate
    // window: a in [k-1, i) -> blocks [tlo, nA). Rotation window: at step k,
    // rotation n > 16-k is dead for EVERY lane. All three windows drop only
    // always-losing candidates; fmaxf reorder is exact -> fin[] bit-identical
    // to the full 256-candidate version. (r9/r10-verified.)
    const int nA = (i_dp + 3) >> 2;   // wave-uniform masked trip count

#define DSTEP(A_, n, MACC)                                                     \
    { float dt_; RORF(dt_, dbase, n); MACC = fmaxf(MACC, dt_ + qr[A_][n]); }
#define AABLOCK(A_, TLO_, NM_)                                                 \
    if (A_ >= (TLO_) && A_ < nA) {                                             \
        const float dbase = Dold[(ksD + A_ * 4) * DSTR + j];                   \
        m0 = fmaxf(m0, dbase + qr[A_][0]);                                     \
        if (1  <= (NM_)) DSTEP(A_, 1, m1)                                      \
        if (2  <= (NM_)) DSTEP(A_, 2, m2)                                      \
        if (3  <= (NM_)) DSTEP(A_, 3, m3)                                      \
        if (4  <= (NM_)) DSTEP(A_, 4, m0)                                      \
        if (5  <= (NM_)) DSTEP(A_, 5, m1)                                      \
        if (6  <= (NM_)) DSTEP(A_, 6, m2)                                      \
        if (7  <= (NM_)) DSTEP(A_, 7, m3)                                      \
        if (8  <= (NM_)) DSTEP(A_, 8, m0)                                      \
        if (9  <= (NM_)) DSTEP(A_, 9, m1)                                      \
        if (10 <= (NM_)) DSTEP(A_, 10, m2)                                     \
        if (11 <= (NM_)) DSTEP(A_, 11, m3)                                     \
        if (12 <= (NM_)) DSTEP(A_, 12, m0)                                     \
        if (13 <= (NM_)) DSTEP(A_, 13, m1)                                     \
        if (14 <= (NM_)) DSTEP(A_, 14, m2)                                     \
        if (15 <= (NM_)) DSTEP(A_, 15, m3)                                     \
    }

    #pragma unroll
    for (int k = 1; k < TT; ++k) {
        const float* Dold = Dm + ((k - 1) & 1) * (TT * DSTR);
        float*       Dnew = Dm + (k & 1)       * (TT * DSTR);
        if (i_dp >= k) {
            const int tlo  = (k - 1) >> 2;    // compile-time after unroll
            const int nmax = 16 - k;          // rotation window, compile-time
            float m0 = -3.0e38f, m1 = -3.0e38f, m2 = -3.0e38f, m3 = -3.0e38f;
            AABLOCK(0, tlo, nmax)
            AABLOCK(1, tlo, nmax)
            AABLOCK(2, tlo, nmax)
            AABLOCK(3, tlo, nmax)
            float mm = fmaxf(fmaxf(m0, m1), fmaxf(m2, m3));
            mm = fmaxf(mm, __shfl_xor(mm, 16));
            mm = fmaxf(mm, __shfl_xor(mm, 32));
            if (ksD == 0) Dnew[i_dp * DSTR + j] = mm;
            if (wv == 0 && lane == 15) fin[k] = mm;
        } else if (ksD == 0) {
            Dnew[i_dp * DSTR + j] = -3.0e38f;  // retired row: garbage, never wins
        }
        __syncthreads();
    }
#undef AABLOCK
#undef DSTEP

    // ================= finalize: serial first-occurrence argmax =================
    if (tid == 0) {
        float best = fin[0];
        int   idx  = 0;
        #pragma unroll
        for (int k = 1; k < TT; ++k) {
            if (fin[k] > best) { best = fin[k]; idx = k; }
        }
        out[b]     = -best;
        out[B + b] = (float)idx;
    }
}

extern "C" void kernel_launch(void* const* d_in, const int* in_sizes, int n_in,
                              void* d_out, int out_size, void* d_ws, size_t ws_size,
                              hipStream_t stream)
{
    const float* f1 = (const float*)d_in[0];
    const float* f2 = (const float*)d_in[1];
    float* out = (float*)d_out;
    const int B = in_sizes[0] / (TT * CC);   // 256
    hipLaunchKernelGGL(cpa_kernel, dim3(B), dim3(1024), 0, stream, f1, f2, out, B);
}